// Round 2
// baseline (1464.554 us; speedup 1.0000x reference)
//
#include <hip/hip_runtime.h>
#include <hip/hip_bf16.h>
#include <cstddef>

// Problem constants (fixed by reference)
#define DD    64      // DIM
#define TT    20      // MAX_NB
#define NSEQ  25600   // B*N = 512*50
#define VV    5       // sequences per wave
#define NWAVE 10
#define BLOCK 640     // NWAVE*64
#define SEQB  50      // NWAVE*VV
#define GRID  512     // NSEQ/SEQB ; = 2*256 CUs exactly

__device__ __forceinline__ float rlane(float v, int l) {
  return __int_as_float(__builtin_amdgcn_readlane(__float_as_int(v), l));
}
__device__ __forceinline__ int rlanei(int v, int l) {
  return __builtin_amdgcn_readlane(v, l);
}

// 64x64 f32 planes, float4-grouped, XOR-swizzled: value W[row][4*dd..4*dd+3]
// stored at float offset row*64 + ((dd ^ (row&15))<<2).  A wave reading
// (fixed dd, row=lane) spreads over all 16 16B-slots per 16-lane group ->
// minimum 2 accesses/bank for a b128 read (free tier, m136).
struct SmemA {            // phase A: central-half weights (64 KB)
  float wihh[3][4096];    // W_ih[:,64:128] by gate
  float aw1h[4096];       // attn_w1[:,64:128]
};
struct SmemB {            // phase B: recurrent + per-t weights (112 KB)
  float whh[3][4096];     // W_hh by gate
  float wihn[3][4096];    // W_ih[:,0:64] by gate
  float aw1g[4096];       // attn_w1[:,0:64]
};

__global__ void __launch_bounds__(BLOCK) gat_gru_fused(
    const int*   __restrict__ g_inputs,   // (B,N)
    const int*   __restrict__ g_nseq,     // (B,N,T)
    const int*   __restrict__ g_nmask,    // (B,N,T)
    const float* __restrict__ g_emb,      // (NUM_NODE, 64)
    const float* __restrict__ g_wih,      // (192,128)
    const float* __restrict__ g_whh,      // (192,64)
    const float* __restrict__ g_bih,      // (192)
    const float* __restrict__ g_bhh,      // (192)
    const float* __restrict__ g_aw1,      // (64,128)
    const float* __restrict__ g_ab1,      // (64)
    const float* __restrict__ g_aw2,      // (64)
    float*       __restrict__ g_out)      // (B,N,64)
{
  union SmemU { SmemA a; SmemB b; };
  __shared__ SmemU sm;
  __shared__ float s_bih[192], s_bhh[192], s_ab1[64], s_aw2[64];

  const int tid   = threadIdx.x;
  const int lane  = tid & 63;
  const int wv    = tid >> 6;
  const int sbase = blockIdx.x * SEQB + wv * VV;
  const int lm    = lane & 15;
  const int lrow  = lane << 6;

  // ---- small constants (persist; outside the union) ----
  if (tid < 192)                      { s_bih[tid] = g_bih[tid]; s_bhh[tid] = g_bhh[tid]; }
  else if (tid >= 256 && tid < 320)   { const int k = tid - 256; s_ab1[k] = g_ab1[k]; s_aw2[k] = g_aw2[k]; }

  // ---- stage phase A: W_ih central half + attn_w1 central half ----
  for (int u = tid; u < 4096; u += BLOCK) {
    const int row = u >> 4, dd = u & 15;
    if (row < 192) {
      const int gate = row >> 6, l = row & 63;
      const float4 val = *(const float4*)(g_wih + row * 128 + 64 + dd * 4);
      *(float4*)&sm.a.wihh[gate][(l << 6) + ((dd ^ (l & 15)) << 2)] = val;
    } else {
      const int k = row - 192;
      const float4 val = *(const float4*)(g_aw1 + k * 128 + 64 + dd * 4);
      *(float4*)&sm.a.aw1h[(k << 6) + ((dd ^ (k & 15)) << 2)] = val;
    }
  }

  // ---- per-sequence gathers (independent of LDS; overlap staging) ----
  int   nsqr[VV], mvr[VV];
  float hemb[VV];
#pragma unroll
  for (int v = 0; v < VV; ++v) {
    const int s  = sbase + v;
    const int ci = g_inputs[s];
    hemb[v] = g_emb[(size_t)ci * DD + lane];
    nsqr[v] = (lane < TT) ? g_nseq[(size_t)s * TT + lane] : 0;
    mvr[v]  = (lane < TT) ? g_nmask[(size_t)s * TT + lane] : 0;
  }

  __syncthreads();

  // ---- normalize central embedding ----
  float hn[VV];
#pragma unroll
  for (int v = 0; v < VV; ++v) {
    const float x = hemb[v];
    float ss = x * x;
#pragma unroll
    for (int m = 1; m < 64; m <<= 1) ss += __shfl_xor(ss, m, 64);
    hn[v] = x / fmaxf(sqrtf(ss), 1e-12f);
  }

  // ---- phase A matvecs: gxh (3 gates, incl. b_ih) and ah (incl. attn_b1) ----
  float gr[VV], gz[VV], gn[VV], ah[VV];
#pragma unroll
  for (int v = 0; v < VV; ++v) {
    gr[v] = s_bih[lane]; gz[v] = s_bih[lane + 64]; gn[v] = s_bih[lane + 128];
    ah[v] = s_ab1[lane];
  }
#pragma unroll 4
  for (int dd = 0; dd < 16; ++dd) {
    const int off = lrow + ((dd ^ lm) << 2);
    const float4 w0 = *(const float4*)&sm.a.wihh[0][off];
    const float4 w1 = *(const float4*)&sm.a.wihh[1][off];
    const float4 w2 = *(const float4*)&sm.a.wihh[2][off];
    const float4 wa = *(const float4*)&sm.a.aw1h[off];
    const int d0 = dd << 2;
#pragma unroll
    for (int v = 0; v < VV; ++v) {
      const float s0 = rlane(hn[v], d0),     s1 = rlane(hn[v], d0 + 1),
                  s2 = rlane(hn[v], d0 + 2), s3 = rlane(hn[v], d0 + 3);
      gr[v] += w0.x * s0 + w0.y * s1 + w0.z * s2 + w0.w * s3;
      gz[v] += w1.x * s0 + w1.y * s1 + w1.z * s2 + w1.w * s3;
      gn[v] += w2.x * s0 + w2.y * s1 + w2.z * s2 + w2.w * s3;
      ah[v] += wa.x * s0 + wa.y * s1 + wa.z * s2 + wa.w * s3;
    }
  }

  __syncthreads();

  // ---- stage phase B (overwrites phase A) ----
  for (int u = tid; u < 7168; u += BLOCK) {
    const int row = u >> 4, dd = u & 15;
    float4 val; float* dst;
    if (row < 192) {
      const int gate = row >> 6, l = row & 63;
      val = *(const float4*)(g_whh + row * 64 + dd * 4);
      dst = &sm.b.whh[gate][(l << 6) + ((dd ^ (l & 15)) << 2)];
    } else if (row < 384) {
      const int r2 = row - 192, gate = r2 >> 6, l = r2 & 63;
      val = *(const float4*)(g_wih + r2 * 128 + dd * 4);
      dst = &sm.b.wihn[gate][(l << 6) + ((dd ^ (l & 15)) << 2)];
    } else {
      const int k = row - 384;
      val = *(const float4*)(g_aw1 + k * 128 + dd * 4);
      dst = &sm.b.aw1g[(k << 6) + ((dd ^ (k & 15)) << 2)];
    }
    *(float4*)dst = val;
  }
  __syncthreads();

  // ---- GRU + fused attention ----
  float h[VV], sc[VV], nbc[VV], nbn[VV];
#pragma unroll
  for (int v = 0; v < VV; ++v) {
    h[v]  = 0.f;
    sc[v] = -1e9f;
    nbc[v] = g_emb[(size_t)rlanei(nsqr[v], 0) * DD + lane];
  }
  const float bhr = s_bhh[lane], bhz = s_bhh[lane + 64], bhn = s_bhh[lane + 128];
  const float w2l = s_aw2[lane];

  auto finalize = [&](float attv, int ttt, int mv, float& scv) {
    float hid = attv > 0.f ? attv : 0.2f * attv;      // LeakyReLU(0.2)
    float p = hid * w2l;
#pragma unroll
    for (int m = 1; m < 64; m <<= 1) p += __shfl_xor(p, m, 64);
    if (lane == ttt && mv != 0) scv = p;              // masked -> keep -1e9
  };

  // t = 0 (h_prev = 0: gh side is just b_hh; no attention yet)
  {
#pragma unroll
    for (int v = 0; v < VV; ++v)
      nbn[v] = g_emb[(size_t)rlanei(nsqr[v], 1) * DD + lane];
    float rx[VV], zx[VV], nx[VV];
#pragma unroll
    for (int v = 0; v < VV; ++v) { rx[v] = gr[v]; zx[v] = gz[v]; nx[v] = gn[v]; }
#pragma unroll 2
    for (int dd = 0; dd < 16; ++dd) {
      const int off = lrow + ((dd ^ lm) << 2);
      const float4 i0 = *(const float4*)&sm.b.wihn[0][off];
      const float4 i1 = *(const float4*)&sm.b.wihn[1][off];
      const float4 i2 = *(const float4*)&sm.b.wihn[2][off];
      const int d0 = dd << 2;
#pragma unroll
      for (int v = 0; v < VV; ++v) {
        const float b0 = rlane(nbc[v], d0),     b1 = rlane(nbc[v], d0 + 1),
                    b2 = rlane(nbc[v], d0 + 2), b3 = rlane(nbc[v], d0 + 3);
        rx[v] += i0.x * b0 + i0.y * b1 + i0.z * b2 + i0.w * b3;
        zx[v] += i1.x * b0 + i1.y * b1 + i1.z * b2 + i1.w * b3;
        nx[v] += i2.x * b0 + i2.y * b1 + i2.z * b2 + i2.w * b3;
      }
    }
#pragma unroll
    for (int v = 0; v < VV; ++v) {
      const float r = 1.f / (1.f + __expf(-(rx[v] + bhr)));
      const float z = 1.f / (1.f + __expf(-(zx[v] + bhz)));
      const float u = __expf(2.f * (nx[v] + r * bhn));
      const float n = 1.f - 2.f / (u + 1.f);          // tanh, NaN-safe at +/-inf
      h[v] = (1.f - z) * n;
      nbc[v] = nbn[v];
    }
  }

  // t = 1..19 : gx(nb_t) + gh(h_{t-1}) + attention score of gru_out[t-1]
  for (int t = 1; t < TT; ++t) {
    if (t + 1 < TT) {
#pragma unroll
      for (int v = 0; v < VV; ++v)
        nbn[v] = g_emb[(size_t)rlanei(nsqr[v], t + 1) * DD + lane];
    }
    float rx[VV], zx[VV], nx[VV], rh[VV], zh[VV], nh[VV], att[VV];
#pragma unroll
    for (int v = 0; v < VV; ++v) {
      rx[v] = gr[v]; zx[v] = gz[v]; nx[v] = gn[v];
      rh[v] = bhr;   zh[v] = bhz;   nh[v] = bhn;
      att[v] = ah[v];
    }
#pragma unroll 2
    for (int dd = 0; dd < 16; ++dd) {
      const int off = lrow + ((dd ^ lm) << 2);
      const float4 i0 = *(const float4*)&sm.b.wihn[0][off];
      const float4 i1 = *(const float4*)&sm.b.wihn[1][off];
      const float4 i2 = *(const float4*)&sm.b.wihn[2][off];
      const float4 h0 = *(const float4*)&sm.b.whh[0][off];
      const float4 h1 = *(const float4*)&sm.b.whh[1][off];
      const float4 h2 = *(const float4*)&sm.b.whh[2][off];
      const float4 wa = *(const float4*)&sm.b.aw1g[off];
      const int d0 = dd << 2;
#pragma unroll
      for (int v = 0; v < VV; ++v) {
        const float b0 = rlane(nbc[v], d0),     b1 = rlane(nbc[v], d0 + 1),
                    b2 = rlane(nbc[v], d0 + 2), b3 = rlane(nbc[v], d0 + 3);
        rx[v] += i0.x * b0 + i0.y * b1 + i0.z * b2 + i0.w * b3;
        zx[v] += i1.x * b0 + i1.y * b1 + i1.z * b2 + i1.w * b3;
        nx[v] += i2.x * b0 + i2.y * b1 + i2.z * b2 + i2.w * b3;
        const float s0 = rlane(h[v], d0),     s1 = rlane(h[v], d0 + 1),
                    s2 = rlane(h[v], d0 + 2), s3 = rlane(h[v], d0 + 3);
        rh[v] += h0.x * s0 + h0.y * s1 + h0.z * s2 + h0.w * s3;
        zh[v] += h1.x * s0 + h1.y * s1 + h1.z * s2 + h1.w * s3;
        nh[v] += h2.x * s0 + h2.y * s1 + h2.z * s2 + h2.w * s3;
        att[v] += wa.x * s0 + wa.y * s1 + wa.z * s2 + wa.w * s3;
      }
    }
#pragma unroll
    for (int v = 0; v < VV; ++v) {
      finalize(att[v], t - 1, mvr[v], sc[v]);
      const float r = 1.f / (1.f + __expf(-(rx[v] + rh[v])));
      const float z = 1.f / (1.f + __expf(-(zx[v] + zh[v])));
      const float u = __expf(2.f * (nx[v] + r * nh[v]));
      const float n = 1.f - 2.f / (u + 1.f);          // tanh, NaN-safe
      h[v] = (1.f - z) * n + z * h[v];
      if (t + 1 < TT) nbc[v] = nbn[v];
    }
  }

  // attention score for gru_out[T-1]
  {
    float att[VV];
#pragma unroll
    for (int v = 0; v < VV; ++v) att[v] = ah[v];
#pragma unroll 4
    for (int dd = 0; dd < 16; ++dd) {
      const int off = lrow + ((dd ^ lm) << 2);
      const float4 wa = *(const float4*)&sm.b.aw1g[off];
      const int d0 = dd << 2;
#pragma unroll
      for (int v = 0; v < VV; ++v) {
        const float s0 = rlane(h[v], d0),     s1 = rlane(h[v], d0 + 1),
                    s2 = rlane(h[v], d0 + 2), s3 = rlane(h[v], d0 + 3);
        att[v] += wa.x * s0 + wa.y * s1 + wa.z * s2 + wa.w * s3;
      }
    }
#pragma unroll
    for (int v = 0; v < VV; ++v) finalize(att[v], TT - 1, mvr[v], sc[v]);
  }

  // ---- softmax over neighbors (lane t holds score t; invalid = -1e9) ----
  float beta[VV], zv[VV];
#pragma unroll
  for (int v = 0; v < VV; ++v) {
    float m = sc[v];
#pragma unroll
    for (int k = 1; k < 64; k <<= 1) m = fmaxf(m, __shfl_xor(m, k, 64));
    const float e = __expf(sc[v] - m);   // masked/empty lanes -> exp(-huge)=0
    float es = e;
#pragma unroll
    for (int k = 1; k < 64; k <<= 1) es += __shfl_xor(es, k, 64);
    beta[v] = e / es;
    zv[v] = 0.f;
  }

  // ---- z = sum_t beta[t] * nb[t]  (re-gather; skip beta==0 -> uniform branch) ----
  for (int t = 0; t < TT; ++t) {
#pragma unroll
    for (int v = 0; v < VV; ++v) {
      const float bt = rlane(beta[v], t);
      if (bt != 0.f)
        zv[v] += bt * g_emb[(size_t)rlanei(nsqr[v], t) * DD + lane];
    }
  }

  // ---- output: z if any neighbor, else normalized central ----
#pragma unroll
  for (int v = 0; v < VV; ++v) {
    const int has = __any(mvr[v] != 0);
    g_out[(size_t)(sbase + v) * DD + lane] = has ? zv[v] : hn[v];
  }
}

extern "C" void kernel_launch(void* const* d_in, const int* in_sizes, int n_in,
                              void* d_out, int out_size, void* d_ws, size_t ws_size,
                              hipStream_t stream) {
  (void)in_sizes; (void)n_in; (void)out_size; (void)d_ws; (void)ws_size;
  gat_gru_fused<<<GRID, BLOCK, 0, stream>>>(
      (const int*)d_in[0], (const int*)d_in[1], (const int*)d_in[2],
      (const float*)d_in[3], (const float*)d_in[4], (const float*)d_in[5],
      (const float*)d_in[6], (const float*)d_in[7], (const float*)d_in[8],
      (const float*)d_in[9], (const float*)d_in[10],
      (float*)d_out);
}

// Round 3
// 1206.867 us; speedup vs baseline: 1.2135x; 1.2135x over previous
//
#include <hip/hip_runtime.h>
#include <cstddef>

// Problem constants
#define DIMD  64
#define TTT   20
#define NSEQ  25600     // 512*50
#define SBLK  50        // sequences per block (padded to M=64 in MFMA)
#define GRID  512       // NSEQ/SBLK = 2 exact rounds of 256 CUs
#define BLOCK 640       // 10 waves
#define NITER 21        // 20 GRU steps + 1 extra pass for score_19
#define PRE_LD 324      // 320 + 4 pad (breaks bank alignment of 320)

typedef __attribute__((ext_vector_type(8))) _Float16 f16x8;
typedef __attribute__((ext_vector_type(4))) float    f32x4;

struct BF { f16x8 hi; f16x8 lo; };

// Split 8 f32 into fp16 hi + exact residual lo (bilinear 3-MFMA => ~f32 grade)
__device__ __forceinline__ void split8(const float* t, f16x8& hi, f16x8& lo) {
#pragma unroll
  for (int j = 0; j < 8; ++j) {
    const float x = t[j];
    const _Float16 h = (_Float16)x;
    hi[j] = h;
    lo[j] = (_Float16)(x - (float)h);
  }
}

// B fragment loader: rowp points at the 32-float k-run for this lane's W row
// (nullptr => zero block). Lane layout: n = lane&15 handled by caller, k-chunk
// = (lane>>4)*8.
__device__ __forceinline__ BF load_bf(const float* rowp, int lane) {
  BF f;
  if (rowp) {
    const float* p = rowp + ((lane >> 4) << 3);
    float t[8];
    *(float4*)&t[0] = *(const float4*)(p);
    *(float4*)&t[4] = *(const float4*)(p + 4);
    split8(t, f.hi, f.lo);
  } else {
#pragma unroll
    for (int j = 0; j < 8; ++j) { f.hi[j] = (_Float16)0.f; f.lo[j] = (_Float16)0.f; }
  }
  return f;
}

// N-column blocks (64 wide): 0:r  1:z  2:nh(h·Whh_n)  3:nx(nb·Wihn_n)  4:attn
// Main-loop B[k][n]: ks 0,1 = h-part rows (k=ks*32..), ks 2,3 = nb-part.
__device__ __forceinline__ const float* bsrc_main(int n, int ks,
    const float* whh, const float* wih, const float* aw1) {
  const int blk = n >> 6;
  if (ks < 2) {                                   // h-part
    if (blk <= 2) return whh + n * 64 + ks * 32;  // r,z,nh: W_hh[n][k]
    if (blk == 3) return nullptr;                 // nx
    return aw1 + (n - 256) * 128 + ks * 32;       // attn: aw1[n'][k]
  } else {                                        // nb-part (kk=(ks-2)*32..)
    if (blk <= 1) return wih + n * 128 + (ks - 2) * 32;        // r,z
    if (blk == 2) return nullptr;                              // nh
    if (blk == 3) return wih + (n - 64) * 128 + (ks - 2) * 32; // nx
    return nullptr;                                            // attn
  }
}
// Phase-0 (central) B0[k][n]: column 64+k of W_ih rows / aw1 rows.
__device__ __forceinline__ const float* bsrc_p0(int n, int ks,
    const float* wih, const float* aw1) {
  const int blk = n >> 6;
  if (blk <= 1) return wih + n * 128 + 64 + ks * 32;
  if (blk == 2) return nullptr;                  // nh: central contributes 0
  if (blk == 3) return wih + (n - 64) * 128 + 64 + ks * 32;
  return aw1 + (n - 256) * 128 + 64 + ks * 32;
}

__device__ __forceinline__ bool bactive(int blk, int ks) {
  if (blk <= 1) return true;        // r,z: all 4 ksteps
  if (blk == 2) return ks < 2;      // nh: h-part only
  if (blk == 3) return ks >= 2;     // nx: nb-part only
  return ks < 2;                    // attn: h-part only
}

__device__ __forceinline__ float biasv(int n, const float* bih,
                                       const float* bhh, const float* ab1) {
  if (n < 128) return bih[n] + bhh[n];   // r,z: combined pre-activation
  if (n < 192) return bhh[n];            // nh
  if (n < 256) return bih[n - 64];       // nx (W_ih rows 128..191)
  return ab1[n - 256];                   // attn
}

__device__ __forceinline__ f32x4 mfma3(f16x8 ah, f16x8 al, const BF& b, f32x4 c) {
  c = __builtin_amdgcn_mfma_f32_16x16x32_f16(ah, b.hi, c, 0, 0, 0);
  c = __builtin_amdgcn_mfma_f32_16x16x32_f16(ah, b.lo, c, 0, 0, 0);
  c = __builtin_amdgcn_mfma_f32_16x16x32_f16(al, b.hi, c, 0, 0, 0);
  return c;
}

__global__ void __launch_bounds__(BLOCK) gat_gru_mfma(
    const int*   __restrict__ g_inputs,
    const int*   __restrict__ g_nseq,
    const int*   __restrict__ g_nmask,
    const float* __restrict__ g_emb,
    const float* __restrict__ g_wih,   // (192,128)
    const float* __restrict__ g_whh,   // (192,64)
    const float* __restrict__ g_bih,   // (192)
    const float* __restrict__ g_bhh,   // (192)
    const float* __restrict__ g_aw1,   // (64,128)
    const float* __restrict__ g_ab1,   // (64)
    const float* __restrict__ g_aw2,   // (64)
    float*       __restrict__ g_out)
{
  // A = [h | nb] staged fp16 hi/lo: 64 rows x 128 cols, 16B-chunk-swizzled
  // byte ^= ((row&7)<<4)  (m214-validated conflict-free pattern for 256B rows)
  __shared__ _Float16 Ahi[64 * 128];       // 16 KB
  __shared__ _Float16 Alo[64 * 128];       // 16 KB
  __shared__ float    PRE[64 * PRE_LD];    // 83 KB pre-activations
  __shared__ float    SC[64 * TTT];        // 5 KB attention scores

  const int tid  = threadIdx.x;
  const int lane = tid & 63;
  const int w    = tid >> 6;
  const int nt0 = w, nt1 = w + 10;               // each wave owns 2 N-tiles
  const int blk0 = nt0 >> 2, blk1 = nt1 >> 2;
  const int sbase = blockIdx.x * SBLK;

  const int al15 = lane & 15, al7 = lane & 7, ahi2 = lane >> 4;
  const int n0 = nt0 * 16 + al15, n1 = nt1 * 16 + al15;

  // pointwise role: 8 threads per sequence
  const int  ps = tid >> 3;                       // 0..63 (valid < SBLK)
  const int  pc = (tid & 7) * 8;                  // feature col base
  const bool pw = (tid < 512) && (ps < SBLK);
  const int  cg = tid & 7;
  const int  offh = ps * 128 + ((cg ^ (ps & 7)) << 3);          // h chunk
  const int  offn = ps * 128 + (((8 + cg) ^ (ps & 7)) << 3);    // nb chunk

  // ---- phase-0 B fragments (central half of W_ih / attn_w1) ----
  BF b0f[2][2];
#pragma unroll
  for (int ks = 0; ks < 2; ++ks) {
    b0f[0][ks] = load_bf(bsrc_p0(n0, ks, g_wih, g_aw1), lane);
    b0f[1][ks] = load_bf(bsrc_p0(n1, ks, g_wih, g_aw1), lane);
  }

  // ---- pw: gather + normalize central embedding, stage into A h-slot ----
  float hn[8];
  if (pw) {
    const int ci = g_inputs[sbase + ps];
    float t[8];
    *(float4*)&t[0] = *(const float4*)(g_emb + (size_t)ci * DIMD + pc);
    *(float4*)&t[4] = *(const float4*)(g_emb + (size_t)ci * DIMD + pc + 4);
    float ss = 0.f;
#pragma unroll
    for (int j = 0; j < 8; ++j) ss += t[j] * t[j];
    ss += __shfl_xor(ss, 1, 64); ss += __shfl_xor(ss, 2, 64); ss += __shfl_xor(ss, 4, 64);
    const float inv = 1.f / fmaxf(sqrtf(ss), 1e-12f);
#pragma unroll
    for (int j = 0; j < 8; ++j) hn[j] = t[j] * inv;
    f16x8 hi, lo; split8(hn, hi, lo);
    *(f16x8*)(Ahi + offh) = hi;
    *(f16x8*)(Alo + offh) = lo;
  }
  __syncthreads();

  // ---- phase-0 matmul: CONST = cent-contributions + biases (stays in regs) ----
  f32x4 cst[2][4];
  {
    f32x4 acc[2][4];
#pragma unroll
    for (int i = 0; i < 2; ++i)
#pragma unroll
      for (int m = 0; m < 4; ++m)
#pragma unroll
        for (int q = 0; q < 4; ++q) acc[i][m][q] = 0.f;
#pragma unroll
    for (int ks = 0; ks < 2; ++ks) {
      f16x8 ah[4], al[4];
#pragma unroll
      for (int m = 0; m < 4; ++m) {
        const int ao = (m * 16 + al15) * 128 + (((ks * 4 + ahi2) ^ al7) << 3);
        ah[m] = *(const f16x8*)(Ahi + ao);
        al[m] = *(const f16x8*)(Alo + ao);
      }
      if (blk0 != 2) {
#pragma unroll
        for (int m = 0; m < 4; ++m) acc[0][m] = mfma3(ah[m], al[m], b0f[0][ks], acc[0][m]);
      }
      if (blk1 != 2) {
#pragma unroll
        for (int m = 0; m < 4; ++m) acc[1][m] = mfma3(ah[m], al[m], b0f[1][ks], acc[1][m]);
      }
    }
    const float bv0 = biasv(n0, g_bih, g_bhh, g_ab1);
    const float bv1 = biasv(n1, g_bih, g_bhh, g_ab1);
#pragma unroll
    for (int m = 0; m < 4; ++m)
#pragma unroll
      for (int q = 0; q < 4; ++q) {
        cst[0][m][q] = acc[0][m][q] + bv0;
        cst[1][m][q] = acc[1][m][q] + bv1;
      }
  }
  __syncthreads();   // phase-0 A-reads complete before h-slot overwrite

  // ---- main B fragments: [Whh|aw1g] (h-part) + [Wihn] (nb-part), in regs ----
  BF bf[2][4];
#pragma unroll
  for (int ks = 0; ks < 4; ++ks) {
    bf[0][ks] = load_bf(bsrc_main(n0, ks, g_whh, g_wih, g_aw1), lane);
    bf[1][ks] = load_bf(bsrc_main(n1, ks, g_whh, g_wih, g_aw1), lane);
  }

  // ---- stage h_{-1}=0 and nb_0 ----
  if (pw) {
    f16x8 z8;
#pragma unroll
    for (int j = 0; j < 8; ++j) z8[j] = (_Float16)0.f;
    *(f16x8*)(Ahi + offh) = z8;
    *(f16x8*)(Alo + offh) = z8;
    const int idx0 = g_nseq[(size_t)(sbase + ps) * TTT + 0];
    float t[8];
    *(float4*)&t[0] = *(const float4*)(g_emb + (size_t)idx0 * DIMD + pc);
    *(float4*)&t[4] = *(const float4*)(g_emb + (size_t)idx0 * DIMD + pc + 4);
    f16x8 hi, lo; split8(t, hi, lo);
    *(f16x8*)(Ahi + offn) = hi;
    *(f16x8*)(Alo + offn) = lo;
  }
  __syncthreads();

  float hprev[8];
#pragma unroll
  for (int j = 0; j < 8; ++j) hprev[j] = 0.f;

  // ================== recurrent loop ==================
  for (int it = 0; it < NITER; ++it) {
    // T14: issue next-neighbor gather early (consumed after the matmul)
    float nbv[8];
    const bool donb = pw && (it <= TTT - 2);
    if (donb) {
      const int idx = g_nseq[(size_t)(sbase + ps) * TTT + it + 1];
      *(float4*)&nbv[0] = *(const float4*)(g_emb + (size_t)idx * DIMD + pc);
      *(float4*)&nbv[4] = *(const float4*)(g_emb + (size_t)idx * DIMD + pc + 4);
    }

    // matmul: OUT = [h_{it-1} | nb_it] @ B  (+CONST via acc init)
    f32x4 acc[2][4];
#pragma unroll
    for (int m = 0; m < 4; ++m)
#pragma unroll
      for (int q = 0; q < 4; ++q) {
        acc[0][m][q] = cst[0][m][q];
        acc[1][m][q] = cst[1][m][q];
      }
#pragma unroll
    for (int ks = 0; ks < 4; ++ks) {
      const bool a0 = bactive(blk0, ks), a1 = bactive(blk1, ks);
      if (a0 || a1) {
        f16x8 ah[4], al[4];
#pragma unroll
        for (int m = 0; m < 4; ++m) {
          const int ao = (m * 16 + al15) * 128 + (((ks * 4 + ahi2) ^ al7) << 3);
          ah[m] = *(const f16x8*)(Ahi + ao);
          al[m] = *(const f16x8*)(Alo + ao);
        }
        if (a0) {
#pragma unroll
          for (int m = 0; m < 4; ++m) acc[0][m] = mfma3(ah[m], al[m], bf[0][ks], acc[0][m]);
        }
        if (a1) {
#pragma unroll
          for (int m = 0; m < 4; ++m) acc[1][m] = mfma3(ah[m], al[m], bf[1][ks], acc[1][m]);
        }
      }
    }
    // write pre-activations (C-layout: col=lane&15, row=(lane>>4)*4+q)
#pragma unroll
    for (int m = 0; m < 4; ++m) {
      const int rb = m * 16 + ahi2 * 4;
#pragma unroll
      for (int q = 0; q < 4; ++q) {
        PRE[(rb + q) * PRE_LD + n0] = acc[0][m][q];
        PRE[(rb + q) * PRE_LD + n1] = acc[1][m][q];
      }
    }
    __syncthreads();

    if (pw) {
      const float* prow = PRE + ps * PRE_LD;
      float rr[8], zz[8], nh[8], nx[8], at[8];
      *(float4*)&rr[0] = *(const float4*)(prow +   0 + pc);
      *(float4*)&rr[4] = *(const float4*)(prow +   4 + pc);
      *(float4*)&zz[0] = *(const float4*)(prow +  64 + pc);
      *(float4*)&zz[4] = *(const float4*)(prow +  68 + pc);
      *(float4*)&nh[0] = *(const float4*)(prow + 128 + pc);
      *(float4*)&nh[4] = *(const float4*)(prow + 132 + pc);
      *(float4*)&nx[0] = *(const float4*)(prow + 192 + pc);
      *(float4*)&nx[4] = *(const float4*)(prow + 196 + pc);
      *(float4*)&at[0] = *(const float4*)(prow + 256 + pc);
      *(float4*)&at[4] = *(const float4*)(prow + 260 + pc);

      // attention score for gru_out[it-1]
      if (it >= 1) {
        float p = 0.f;
#pragma unroll
        for (int j = 0; j < 8; ++j) {
          const float a = at[j];
          p += g_aw2[pc + j] * (a > 0.f ? a : 0.2f * a);   // LeakyReLU(0.2)
        }
        p += __shfl_xor(p, 1, 64); p += __shfl_xor(p, 2, 64); p += __shfl_xor(p, 4, 64);
        if (cg == 0) SC[ps * TTT + (it - 1)] = p;
      }
      // GRU pointwise update
      if (it < TTT) {
        float hnew[8];
#pragma unroll
        for (int j = 0; j < 8; ++j) {
          const float r = 1.f / (1.f + __expf(-rr[j]));
          const float z = 1.f / (1.f + __expf(-zz[j]));
          const float u = __expf(2.f * (nx[j] + r * nh[j]));
          const float n = 1.f - 2.f / (u + 1.f);           // NaN-safe tanh
          hnew[j] = (1.f - z) * n + z * hprev[j];
          hprev[j] = hnew[j];
        }
        f16x8 hi, lo; split8(hnew, hi, lo);
        *(f16x8*)(Ahi + offh) = hi;
        *(f16x8*)(Alo + offh) = lo;
      }
      if (donb) {
        f16x8 hi, lo; split8(nbv, hi, lo);
        *(f16x8*)(Ahi + offn) = hi;
        *(f16x8*)(Alo + offn) = lo;
      }
    }
    __syncthreads();
  }

  // ================== epilogue: softmax + z-aggregation ==================
  if (pw) {
    const int s = sbase + ps;
    int mbits = 0;
    float mx = -1e30f;
#pragma unroll
    for (int t = 0; t < TTT; ++t) {
      if (g_nmask[(size_t)s * TTT + t]) {
        mbits |= (1 << t);
        mx = fmaxf(mx, SC[ps * TTT + t]);
      }
    }
    float sum = 0.f, za[8];
#pragma unroll
    for (int j = 0; j < 8; ++j) za[j] = 0.f;
    for (int t = 0; t < TTT; ++t) {
      if (mbits & (1 << t)) {
        const float e = __expf(SC[ps * TTT + t] - mx);
        sum += e;
        const int idx = g_nseq[(size_t)s * TTT + t];
        float4 e0 = *(const float4*)(g_emb + (size_t)idx * DIMD + pc);
        float4 e1 = *(const float4*)(g_emb + (size_t)idx * DIMD + pc + 4);
        za[0] += e * e0.x; za[1] += e * e0.y; za[2] += e * e0.z; za[3] += e * e0.w;
        za[4] += e * e1.x; za[5] += e * e1.y; za[6] += e * e1.z; za[7] += e * e1.w;
      }
    }
    float o[8];
    if (mbits) {
      const float inv = 1.f / sum;
#pragma unroll
      for (int j = 0; j < 8; ++j) o[j] = za[j] * inv;
    } else {
#pragma unroll
      for (int j = 0; j < 8; ++j) o[j] = hn[j];
    }
    float4 o0, o1;
    o0.x = o[0]; o0.y = o[1]; o0.z = o[2]; o0.w = o[3];
    o1.x = o[4]; o1.y = o[5]; o1.z = o[6]; o1.w = o[7];
    *(float4*)(g_out + (size_t)s * DIMD + pc)     = o0;
    *(float4*)(g_out + (size_t)s * DIMD + pc + 4) = o1;
  }
}

extern "C" void kernel_launch(void* const* d_in, const int* in_sizes, int n_in,
                              void* d_out, int out_size, void* d_ws, size_t ws_size,
                              hipStream_t stream) {
  (void)in_sizes; (void)n_in; (void)out_size; (void)d_ws; (void)ws_size;
  gat_gru_mfma<<<GRID, BLOCK, 0, stream>>>(
      (const int*)d_in[0], (const int*)d_in[1], (const int*)d_in[2],
      (const float*)d_in[3], (const float*)d_in[4], (const float*)d_in[5],
      (const float*)d_in[6], (const float*)d_in[7], (const float*)d_in[8],
      (const float*)d_in[9], (const float*)d_in[10],
      (float*)d_out);
}

// Round 7
// 733.009 us; speedup vs baseline: 1.9980x; 1.6465x over previous
//
#include <hip/hip_runtime.h>
#include <cstddef>

#define TTT   20
#define SBLK  16
#define GRIDN 1600      // 25600/16
#define BLOCK 256       // 4 waves

typedef __attribute__((ext_vector_type(8))) _Float16 f16x8;
typedef __attribute__((ext_vector_type(4))) _Float16 f16x4;
typedef __attribute__((ext_vector_type(4))) float    f32x4;

struct BF { f16x8 hi, lo; };

// B fragment: lane provides B[k][n=f] = W[f][k], k = kbase + (lane>>4)*8 + j
__device__ __forceinline__ BF load_bf(const float* rowp, int lane) {
  BF fr;
  const float* p = rowp + ((lane >> 4) << 3);
  float t[8];
  *(float4*)&t[0] = *(const float4*)(p);
  *(float4*)&t[4] = *(const float4*)(p + 4);
#pragma unroll
  for (int jj = 0; jj < 8; ++jj) {
    const _Float16 h = (_Float16)t[jj];
    fr.hi[jj] = h;
    fr.lo[jj] = (_Float16)(t[jj] - (float)h);
  }
  return fr;
}

// bilinear 3-term split: AhBh + AhBl + AlBh  (~f32-grade)
__device__ __forceinline__ f32x4 mfma3(f16x8 ah, f16x8 al, const BF& b, f32x4 c) {
  c = __builtin_amdgcn_mfma_f32_16x16x32_f16(ah, b.hi, c, 0, 0, 0);
  c = __builtin_amdgcn_mfma_f32_16x16x32_f16(ah, b.lo, c, 0, 0, 0);
  c = __builtin_amdgcn_mfma_f32_16x16x32_f16(al, b.hi, c, 0, 0, 0);
  return c;
}

__global__ void __launch_bounds__(BLOCK, 2) gat_gru_v2(
    const int*   __restrict__ g_inputs,
    const int*   __restrict__ g_nseq,
    const int*   __restrict__ g_nmask,
    const float* __restrict__ g_emb,
    const float* __restrict__ g_wih,   // (192,128)
    const float* __restrict__ g_whh,   // (192,64)
    const float* __restrict__ g_bih,
    const float* __restrict__ g_bhh,
    const float* __restrict__ g_aw1,   // (64,128)
    const float* __restrict__ g_ab1,
    const float* __restrict__ g_aw2,
    float*       __restrict__ g_out)
{
  // A in MFMA-fragment order: elem((k,row)) = ((k>>3)*16 + row)*8 + (k&7)
  // -> a wave's A-frag read (ks) is a CONTIGUOUS 1KB region (conflict-free).
  __shared__ _Float16 AFhi[2][2048];     // 2 buffers x 16 rows x 128 k
  __shared__ _Float16 AFlo[2][2048];
  __shared__ float    SCP[TTT * 4 * 16]; // [t][wave][seq] score partials
  __shared__ float    SC2[16 * TTT];     // [s][t] masked scores
  __shared__ float    BB [16 * TTT];     // [s][t] betas
  __shared__ float    HN [16 * 64];      // normalized central
  __shared__ int      HAS[16];

  const int tid  = threadIdx.x;
  const int lane = tid & 63;
  const int w    = tid >> 6;
  const int s    = tid >> 4;          // gather/pointwise role: seq 0..15
  const int j    = tid & 15;          //                        col group
  const int g    = lane >> 4;
  const int f    = w * 16 + (lane & 15);   // this lane's feature column
  const int sbase = blockIdx.x * SBLK;
  const size_t snb = (size_t)(sbase + s) * TTT;

  // ---- early global loads ----
  const int ci = g_inputs[sbase + s];
  const float4 cent0 = *(const float4*)(g_emb + (size_t)ci * 64 + j * 4);
  const int idx0 = g_nseq[snb];
  const float4 nb0 = *(const float4*)(g_emb + (size_t)idx0 * 64 + j * 4);

  const float w2f  = g_aw2[f];
  const float bihr = g_bih[f], bihz = g_bih[64 + f], bihn = g_bih[128 + f];
  const float bhhr = g_bhh[f], bhhz = g_bhh[64 + f], bhhn = g_bhh[128 + f];
  const float ab1f = g_ab1[f];

  // ---- phase-0 B fragments (central columns 64..127) ----
  BF B0r[2], B0z[2], B0nx[2], B0at[2];
#pragma unroll
  for (int k2 = 0; k2 < 2; ++k2) {
    B0r[k2]  = load_bf(g_wih + (size_t)f * 128         + 64 + k2 * 32, lane);
    B0z[k2]  = load_bf(g_wih + (size_t)(64 + f) * 128  + 64 + k2 * 32, lane);
    B0nx[k2] = load_bf(g_wih + (size_t)(128 + f) * 128 + 64 + k2 * 32, lane);
    B0at[k2] = load_bf(g_aw1 + (size_t)f * 128         + 64 + k2 * 32, lane);
  }

  // ---- normalize central embedding, stage into AF[0] h-slot ----
  float hv4[4] = {cent0.x, cent0.y, cent0.z, cent0.w};
  {
    float ssum = hv4[0]*hv4[0] + hv4[1]*hv4[1] + hv4[2]*hv4[2] + hv4[3]*hv4[3];
    ssum += __shfl_xor(ssum, 1, 64); ssum += __shfl_xor(ssum, 2, 64);
    ssum += __shfl_xor(ssum, 4, 64); ssum += __shfl_xor(ssum, 8, 64);
    const float inv = 1.f / fmaxf(sqrtf(ssum), 1e-12f);
#pragma unroll
    for (int c = 0; c < 4; ++c) hv4[c] *= inv;
    *(float4*)&HN[s * 64 + j * 4] = *(float4*)hv4;
    const int k0 = 4 * j;
    const int e  = ((k0 >> 3) * 16 + s) * 8 + (k0 & 7);
    f16x4 hi, lo;
#pragma unroll
    for (int c = 0; c < 4; ++c) {
      hi[c] = (_Float16)hv4[c];
      lo[c] = (_Float16)(hv4[c] - (float)hi[c]);
    }
    *(f16x4*)&AFhi[0][e] = hi;
    *(f16x4*)&AFlo[0][e] = lo;
  }
  __syncthreads();

  // ---- phase-0 matmul -> per-lane constants (central contrib + biases) ----
  f32x4 cr, cz, cnh, cnx, cat;
  {
    f32x4 a_r, a_z, a_nx, a_at;
#pragma unroll
    for (int q = 0; q < 4; ++q) { a_r[q] = 0.f; a_z[q] = 0.f; a_nx[q] = 0.f; a_at[q] = 0.f; }
#pragma unroll
    for (int k2 = 0; k2 < 2; ++k2) {
      const f16x8 ah = *(const f16x8*)&AFhi[0][k2 * 512 + lane * 8];
      const f16x8 al = *(const f16x8*)&AFlo[0][k2 * 512 + lane * 8];
      a_r  = mfma3(ah, al, B0r[k2],  a_r);
      a_z  = mfma3(ah, al, B0z[k2],  a_z);
      a_nx = mfma3(ah, al, B0nx[k2], a_nx);
      a_at = mfma3(ah, al, B0at[k2], a_at);
    }
#pragma unroll
    for (int q = 0; q < 4; ++q) {
      cr[q]  = a_r[q]  + bihr + bhhr;
      cz[q]  = a_z[q]  + bihz + bhhz;
      cnh[q] = bhhn;
      cnx[q] = a_nx[q] + bihn;
      cat[q] = a_at[q] + ab1f;
    }
  }

  // ---- stage AF[1]: h_{-1}=0 and nb_0 ----
  {
    const int k0 = 4 * j;
    const int e  = ((k0 >> 3) * 16 + s) * 8 + (k0 & 7);
    f16x4 z4;
#pragma unroll
    for (int c = 0; c < 4; ++c) z4[c] = (_Float16)0.f;
    *(f16x4*)&AFhi[1][e] = z4;
    *(f16x4*)&AFlo[1][e] = z4;
    const int k1 = 64 + 4 * j;
    const int e1 = ((k1 >> 3) * 16 + s) * 8 + (k1 & 7);
    float tv[4] = {nb0.x, nb0.y, nb0.z, nb0.w};
    f16x4 hi, lo;
#pragma unroll
    for (int c = 0; c < 4; ++c) {
      hi[c] = (_Float16)tv[c];
      lo[c] = (_Float16)(tv[c] - (float)hi[c]);
    }
    *(f16x4*)&AFhi[1][e1] = hi;
    *(f16x4*)&AFlo[1][e1] = lo;
  }

  // ---- main-loop B fragments (held in registers for the whole loop) ----
  BF Br[4], Bz[4], Bnh[2], Bnx[2], Bat[2];
#pragma unroll
  for (int k2 = 0; k2 < 2; ++k2) {
    Br[k2]     = load_bf(g_whh + (size_t)f * 64          + k2 * 32, lane);
    Br[2 + k2] = load_bf(g_wih + (size_t)f * 128         + k2 * 32, lane);
    Bz[k2]     = load_bf(g_whh + (size_t)(64 + f) * 64   + k2 * 32, lane);
    Bz[2 + k2] = load_bf(g_wih + (size_t)(64 + f) * 128  + k2 * 32, lane);
    Bnh[k2]    = load_bf(g_whh + (size_t)(128 + f) * 64  + k2 * 32, lane);
    Bnx[k2]    = load_bf(g_wih + (size_t)(128 + f) * 128 + k2 * 32, lane);
    Bat[k2]    = load_bf(g_aw1 + (size_t)f * 128         + k2 * 32, lane);
  }
  float hp[4] = {0.f, 0.f, 0.f, 0.f};
  __syncthreads();

  // ================== recurrent loop: ONE barrier per iteration ==================
  for (int it = 0; it <= TTT; ++it) {
    const int rd  = (it + 1) & 1;
    const int wrb = it & 1;
    const bool full = (it < TTT);
    const bool dog  = (it < TTT - 1);
    float4 nb4;
    if (dog) {                      // T14: issue next-nb gather early
      const int idx = g_nseq[snb + it + 1];
      nb4 = *(const float4*)(g_emb + (size_t)idx * 64 + j * 4);
    }

    f32x4 ar = cr, az = cz, anh = cnh, anx = cnx, aat = cat;
#pragma unroll
    for (int k2 = 0; k2 < 2; ++k2) {   // h-part (k 0..63)
      const f16x8 ah = *(const f16x8*)&AFhi[rd][k2 * 512 + lane * 8];
      const f16x8 al = *(const f16x8*)&AFlo[rd][k2 * 512 + lane * 8];
      aat = mfma3(ah, al, Bat[k2], aat);
      if (full) {
        ar  = mfma3(ah, al, Br[k2],  ar);
        az  = mfma3(ah, al, Bz[k2],  az);
        anh = mfma3(ah, al, Bnh[k2], anh);
      }
    }
    if (full) {
#pragma unroll
      for (int k2 = 0; k2 < 2; ++k2) { // nb-part (k 64..127)
        const f16x8 ah = *(const f16x8*)&AFhi[rd][(2 + k2) * 512 + lane * 8];
        const f16x8 al = *(const f16x8*)&AFlo[rd][(2 + k2) * 512 + lane * 8];
        ar  = mfma3(ah, al, Br[2 + k2], ar);
        az  = mfma3(ah, al, Bz[2 + k2], az);
        anx = mfma3(ah, al, Bnx[k2],    anx);
      }
    }

    // attention score partial for gru_out[it-1] (uses OLD h via aat)
    if (it >= 1) {
      float c0, c1, c2, c3;
      {
        float a;
        a = aat[0]; c0 = w2f * (a > 0.f ? a : 0.2f * a);
        a = aat[1]; c1 = w2f * (a > 0.f ? a : 0.2f * a);
        a = aat[2]; c2 = w2f * (a > 0.f ? a : 0.2f * a);
        a = aat[3]; c3 = w2f * (a > 0.f ? a : 0.2f * a);
      }
#pragma unroll
      for (int m = 1; m < 16; m <<= 1) {
        c0 += __shfl_xor(c0, m, 64); c1 += __shfl_xor(c1, m, 64);
        c2 += __shfl_xor(c2, m, 64); c3 += __shfl_xor(c3, m, 64);
      }
      if ((lane & 15) == 0) {
        float4 pv; pv.x = c0; pv.y = c1; pv.z = c2; pv.w = c3;
        *(float4*)&SCP[((it - 1) * 4 + w) * 16 + g * 4] = pv;
      }
    }

    if (full) {
      // GRU pointwise — entirely in-lane (lane holds r,z,nh,nx for its (s,f))
      const int kc = f >> 3, fb = f & 7;
#pragma unroll
      for (int q = 0; q < 4; ++q) {
        const float r  = 1.f / (1.f + __expf(-ar[q]));
        const float zz = 1.f / (1.f + __expf(-az[q]));
        const float u  = __expf(2.f * (anx[q] + r * anh[q]));
        const float n  = 1.f - 2.f / (u + 1.f);      // NaN-safe tanh
        const float hnew = (1.f - zz) * n + zz * hp[q];
        hp[q] = hnew;
        const _Float16 hh = (_Float16)hnew;
        const int e = (kc * 16 + g * 4 + q) * 8 + fb;
        AFhi[wrb][e] = hh;
        AFlo[wrb][e] = (_Float16)(hnew - (float)hh);
      }
      if (dog) {
        const int k1 = 64 + 4 * j;
        const int e1 = ((k1 >> 3) * 16 + s) * 8 + (k1 & 7);
        float tv[4] = {nb4.x, nb4.y, nb4.z, nb4.w};
        f16x4 hi, lo;
#pragma unroll
        for (int c = 0; c < 4; ++c) {
          hi[c] = (_Float16)tv[c];
          lo[c] = (_Float16)(tv[c] - (float)hi[c]);
        }
        *(f16x4*)&AFhi[wrb][e1] = hi;
        *(f16x4*)&AFlo[wrb][e1] = lo;
      }
    }
    __syncthreads();
  }

  // ================== epilogue ==================
  // E1: combine 4 wave-partials per score, apply mask
  {
    const int s1 = tid & 15, t0 = tid >> 4;
#pragma unroll
    for (int rep = 0; rep < 2; ++rep) {
      const int t = t0 + rep * 16;
      if (t < TTT) {
        const float sc = SCP[t * 64 + s1] + SCP[t * 64 + 16 + s1] +
                         SCP[t * 64 + 32 + s1] + SCP[t * 64 + 48 + s1];
        const int mk = g_nmask[(size_t)(sbase + s1) * TTT + t];
        SC2[s1 * TTT + t] = mk ? sc : -1e30f;
      }
    }
  }
  __syncthreads();
  // E2: per-seq softmax over 20 (16 threads per seq)
  {
    const float v0 = SC2[s * TTT + j];
    const float v1 = (j < 4) ? SC2[s * TTT + 16 + j] : -1e30f;
    float mx = fmaxf(v0, v1);
#pragma unroll
    for (int m = 1; m < 16; m <<= 1) mx = fmaxf(mx, __shfl_xor(mx, m, 64));
    const float e0 = (v0 > -1e29f) ? __expf(v0 - mx) : 0.f;
    const float e1 = (v1 > -1e29f) ? __expf(v1 - mx) : 0.f;
    float sm = e0 + e1;
#pragma unroll
    for (int m = 1; m < 16; m <<= 1) sm += __shfl_xor(sm, m, 64);
    const float rinv = (sm > 0.f) ? 1.f / sm : 0.f;
    BB[s * TTT + j] = e0 * rinv;
    if (j < 4) BB[s * TTT + 16 + j] = e1 * rinv;
    if (j == 0) HAS[s] = (sm > 0.f) ? 1 : 0;
  }
  __syncthreads();
  // E3: z = sum_t beta_t * nb_t  (coalesced 256B row re-gather)
  {
    float za[4] = {0.f, 0.f, 0.f, 0.f};
    for (int t = 0; t < TTT; ++t) {
      const float b = BB[s * TTT + t];
      if (b != 0.f) {
        const int idx = g_nseq[snb + t];
        const float4 e4 = *(const float4*)(g_emb + (size_t)idx * 64 + j * 4);
        za[0] += b * e4.x; za[1] += b * e4.y; za[2] += b * e4.z; za[3] += b * e4.w;
      }
    }
    float4 o;
    if (HAS[s]) { o.x = za[0]; o.y = za[1]; o.z = za[2]; o.w = za[3]; }
    else        { o = *(float4*)&HN[s * 64 + j * 4]; }
    *(float4*)(g_out + (size_t)(sbase + s) * 64 + j * 4) = o;
  }
}

extern "C" void kernel_launch(void* const* d_in, const int* in_sizes, int n_in,
                              void* d_out, int out_size, void* d_ws, size_t ws_size,
                              hipStream_t stream) {
  (void)in_sizes; (void)n_in; (void)out_size; (void)d_ws; (void)ws_size;
  gat_gru_v2<<<GRIDN, BLOCK, 0, stream>>>(
      (const int*)d_in[0], (const int*)d_in[1], (const int*)d_in[2],
      (const float*)d_in[3], (const float*)d_in[4], (const float*)d_in[5],
      (const float*)d_in[6], (const float*)d_in[7], (const float*)d_in[8],
      (const float*)d_in[9], (const float*)d_in[10],
      (float*)d_out);
}